// Round 2
// baseline (352.120 us; speedup 1.0000x reference)
//
#include <hip/hip_runtime.h>
#include <hip/hip_bf16.h>
#include <stdint.h>

// ---------------------------------------------------------------------------
// TensorizedGRU: m[b,l] = sum_{j,k} s[b,j] x[b,k] W[l,j,k]  (l in [0,256): W1||W2)
// GEMM M=4096 N=256 K=65536 with virtual A: P[b, j*256+kk] = s[b,j]*x[b,kk]
// ws layout:
//   Wt   bf16 [256][65536]  @ 0         (33,554,432 B)  == W1||W2 cast to bf16
//   s_bf bf16 [4096][256]   @ 32 MiB    ( 2,097,152 B)
//   x_bf bf16 [4096][256]   @ +2 MiB    ( 2,097,152 B)
//   Mpart f32 [8][4096][256]@ +2 MiB    (33,554,432 B)  split-K partials
// ---------------------------------------------------------------------------

typedef short bf8 __attribute__((ext_vector_type(8)));   // 8 bf16 = 4 VGPRs
typedef float f32x4 __attribute__((ext_vector_type(4)));

static constexpr size_t WT_OFF  = 0;
static constexpr size_t SBF_OFF = 33554432;
static constexpr size_t XBF_OFF = SBF_OFF + 2097152;
static constexpr size_t MP_OFF  = XBF_OFF + 2097152;

// round-to-nearest-even f32 -> bf16 (finite inputs only)
__device__ __forceinline__ unsigned f2bf(float f) {
    unsigned u = __builtin_bit_cast(unsigned, f);
    return (u + 0x7fffu + ((u >> 16) & 1u)) >> 16;
}
__device__ __forceinline__ unsigned pack2bf(float a, float b) {
    return f2bf(a) | (f2bf(b) << 16);
}
// u holds two bf16 (lo = lower address). Return bf16x2 of (lo*s, hi*s).
__device__ __forceinline__ unsigned mulbf2(unsigned u, float s) {
    float lo = __builtin_bit_cast(float, u << 16);
    float hi = __builtin_bit_cast(float, u & 0xffff0000u);
    return pack2bf(lo * s, hi * s);
}

// ---------------- prep: weights f32 -> bf16 (layout already [n][K]) ---------
__global__ void prep_w(const float* __restrict__ W1, const float* __restrict__ W2,
                       unsigned* __restrict__ Wt) {
    unsigned u = blockIdx.x * 256 + threadIdx.x;      // 2,097,152 units of 8 elems
    size_t e = (size_t)u * 8;
    unsigned n = (unsigned)(e >> 16);
    unsigned k = (unsigned)(e & 65535u);
    const float* src = (n < 128 ? W1 + ((size_t)n << 16)
                                : W2 + ((size_t)(n - 128) << 16)) + k;
    float4 a = ((const float4*)src)[0];
    float4 b = ((const float4*)src)[1];
    uint4 o;
    o.x = pack2bf(a.x, a.y); o.y = pack2bf(a.z, a.w);
    o.z = pack2bf(b.x, b.y); o.w = pack2bf(b.z, b.w);
    ((uint4*)Wt)[u] = o;
}

// ---------------- prep: s = st0||st1, x = in0||in1 -> bf16 ------------------
__global__ void prep_sx(const float* __restrict__ in0, const float* __restrict__ in1,
                        const float* __restrict__ st0, const float* __restrict__ st1,
                        unsigned* __restrict__ s_bf, unsigned* __restrict__ x_bf) {
    unsigned u = blockIdx.x * 256 + threadIdx.x;      // 524,288 units of 4 elems
    unsigned which = u >> 18;                         // 0: s, 1: x
    unsigned v = u & 262143u;
    unsigned b = v >> 6;
    unsigned j4 = (v & 63u) * 4u;
    const float* loH = which ? in0 : st0;
    const float* hiH = which ? in1 : st1;
    const float* src = (j4 < 128) ? (loH + (size_t)b * 128 + j4)
                                  : (hiH + (size_t)b * 128 + (j4 - 128));
    float4 a = *(const float4*)src;
    uint2 o;
    o.x = pack2bf(a.x, a.y);
    o.y = pack2bf(a.z, a.w);
    unsigned* dst = which ? x_bf : s_bf;
    ((uint2*)dst)[v] = o;
}

// ---------------- main GEMM: 128x128 tile, split-K=8, BK=64 -----------------
// grid 512 = 32 Mtiles x 2 Ntiles x 8 Ksplits; block 256 = 4 waves (64x64 each)
__launch_bounds__(256, 2)
__global__ void gemm_p(const __hip_bfloat16* __restrict__ Wt,
                       const unsigned short* __restrict__ s_bf,
                       const __hip_bfloat16* __restrict__ x_bf,
                       float* __restrict__ Mpart) {
    const int bx = blockIdx.x;
    const int mt = bx & 31;
    const int nt = (bx >> 5) & 1;
    const int ks = bx >> 6;                 // 0..7, each covers K-range 8192 (32 j's)
    const int b0 = mt << 7, n0 = nt << 7;
    const int tid  = threadIdx.x;
    const int lane = tid & 63, wave = tid >> 6;
    const int wm = wave & 1, wn = wave >> 1;

    // W tile: 128 n-rows x 64 k, XOR-swizzled 16B slots (global_load_lds forbids pad)
    __shared__ __align__(16) unsigned char Wl[16384];
    // P tile: 128 b-rows x 64 k, padded row stride 144 B (+16B) -> 2-way conflicts max
    __shared__ __align__(16) unsigned char Pl[128 * 144];

    // --- staging precompute: 4 global_load_lds (16B/lane) per thread per chunk
    const __hip_bfloat16* wgp[4];
    unsigned char* wlp[4];
    #pragma unroll
    for (int i = 0; i < 4; ++i) {
        int slot = (wave * 4 + i) * 64 + lane;       // 16B-slot index 0..1023
        int r = slot >> 3;                           // n-row 0..127
        int g = (slot & 7) ^ (r & 7);                // swizzled k-group
        wgp[i] = Wt + (((size_t)(n0 + r)) << 16) + g * 8;
        wlp[i] = Wl + (wave * 4 + i) * 1024;         // wave-uniform base (+lane*16 by HW)
    }

    // --- P-gen precompute: thread -> (row pr, half ph), 32 elems/chunk
    const int pr = tid >> 1, ph = tid & 1;
    const __hip_bfloat16* xgp = x_bf + (((size_t)(b0 + pr)) << 8) + ph * 32;
    const unsigned short* sgp = s_bf + (((size_t)(b0 + pr)) << 8) + ks * 32;
    unsigned char* pwp = Pl + pr * 144 + ph * 64;

    // --- fragment read bases
    const int arow = wm * 64 + (lane & 15);
    const int acol = lane >> 4;                      // k-quad
    const unsigned char* pA = Pl + arow * 144 + acol * 16;
    const int brow = wn * 64 + (lane & 15);
    const int be = brow & 7;
    const unsigned char* pB = Wl + brow * 128;

    f32x4 acc[4][4];
    #pragma unroll
    for (int i = 0; i < 4; ++i)
        #pragma unroll
        for (int j = 0; j < 4; ++j)
            acc[i][j] = (f32x4){0.f, 0.f, 0.f, 0.f};

    const int kbase = ks * 8192;
    for (int c = 0; c < 128; ++c) {
        const int koff = kbase + (c >> 2) * 256 + (c & 3) * 64; // j=ks*32+(c>>2)
        // async stage W chunk (vmcnt; drained by the barrier)
        #pragma unroll
        for (int i = 0; i < 4; ++i) {
            __builtin_amdgcn_global_load_lds(
                (__attribute__((address_space(1))) const unsigned*)(const void*)(wgp[i] + koff),
                (__attribute__((address_space(3))) unsigned*)(void*)wlp[i],
                16, 0, 0);
        }
        // P-gen: P[pr][kk] = s[pr][j] * x[pr][kk] in bf16
        {
            float sf = __builtin_bit_cast(float, ((unsigned)sgp[c >> 2]) << 16);
            const uint4* xs = (const uint4*)(xgp + (c & 3) * 64);
            uint4 x0 = xs[0], x1 = xs[1], x2 = xs[2], x3 = xs[3];
            uint4 o0, o1, o2, o3;
            o0.x = mulbf2(x0.x, sf); o0.y = mulbf2(x0.y, sf);
            o0.z = mulbf2(x0.z, sf); o0.w = mulbf2(x0.w, sf);
            o1.x = mulbf2(x1.x, sf); o1.y = mulbf2(x1.y, sf);
            o1.z = mulbf2(x1.z, sf); o1.w = mulbf2(x1.w, sf);
            o2.x = mulbf2(x2.x, sf); o2.y = mulbf2(x2.y, sf);
            o2.z = mulbf2(x2.z, sf); o2.w = mulbf2(x2.w, sf);
            o3.x = mulbf2(x3.x, sf); o3.y = mulbf2(x3.y, sf);
            o3.z = mulbf2(x3.z, sf); o3.w = mulbf2(x3.w, sf);
            uint4* pw = (uint4*)pwp;
            pw[0] = o0; pw[1] = o1; pw[2] = o2; pw[3] = o3;
        }
        __syncthreads();   // drains global_load_lds + makes P visible
        #pragma unroll
        for (int kst = 0; kst < 2; ++kst) {
            bf8 Af[4], Bf[4];
            #pragma unroll
            for (int mf = 0; mf < 4; ++mf)
                Af[mf] = *(const bf8*)(pA + mf * (16 * 144) + kst * 64);
            #pragma unroll
            for (int nf = 0; nf < 4; ++nf) {
                int g = (kst * 4 + acol) ^ be;       // un-swizzle
                Bf[nf] = *(const bf8*)(pB + nf * (16 * 128) + g * 16);
            }
            #pragma unroll
            for (int mf = 0; mf < 4; ++mf)
                #pragma unroll
                for (int nf = 0; nf < 4; ++nf)
                    acc[mf][nf] = __builtin_amdgcn_mfma_f32_16x16x32_bf16(
                        Af[mf], Bf[nf], acc[mf][nf], 0, 0, 0);
        }
        __syncthreads();   // reads done before next chunk overwrites LDS
    }

    // write split-K partials; C/D: row=(lane>>4)*4+reg (b), col=lane&15 (n)
    float* mp = Mpart + ((size_t)ks << 20);
    const int rowb = b0 + wm * 64 + (lane >> 4) * 4;
    const int colb = n0 + wn * 64 + (lane & 15);
    #pragma unroll
    for (int mf = 0; mf < 4; ++mf)
        #pragma unroll
        for (int nf = 0; nf < 4; ++nf) {
            int b = rowb + mf * 16;
            int n = colb + nf * 16;
            #pragma unroll
            for (int r = 0; r < 4; ++r)
                mp[(size_t)(b + r) * 256 + n] = acc[mf][nf][r];
        }
}

// ---------------- epilogue: reduce split-K, s@W3, activations, blend --------
__global__ void epilogue(const float* __restrict__ st0, const float* __restrict__ st1,
                         const float* __restrict__ b1, const float* __restrict__ b2,
                         const float* __restrict__ W3, const float* __restrict__ Mpart,
                         float* __restrict__ out) {
    const int tid = threadIdx.x;
    const int h = tid & 127, rg = tid >> 7;          // rg in {0,1}
    const int bbase = blockIdx.x * 8;                // 8 rows per block
    __shared__ float srow[8][256];
    #pragma unroll
    for (int i = 0; i < 8; ++i) {
        int idx = i * 256 + tid;
        int r = idx >> 8, j = idx & 255;
        float v = (j < 128) ? st0[(size_t)(bbase + r) * 128 + j]
                            : st1[(size_t)(bbase + r) * 128 + (j - 128)];
        srow[r][j] = v;
    }
    __syncthreads();
    float acc0 = 0.f, acc1 = 0.f, acc2 = 0.f, acc3 = 0.f;
    for (int j = 0; j < 256; ++j) {
        float w = W3[j * 128 + h];
        acc0 += srow[rg][j] * w;
        acc1 += srow[rg + 2][j] * w;
        acc2 += srow[rg + 4][j] * w;
        acc3 += srow[rg + 6][j] * w;
    }
    float accs[4] = {acc0, acc1, acc2, acc3};
    float bb1 = b1[h], bb2 = b2[h];
    #pragma unroll
    for (int i = 0; i < 4; ++i) {
        int b = bbase + rg + i * 2;
        float m1 = 0.f, m2 = 0.f;
        #pragma unroll
        for (int k = 0; k < 8; ++k) {
            m1 += Mpart[((size_t)k << 20) + (size_t)b * 256 + h];
            m2 += Mpart[((size_t)k << 20) + (size_t)b * 256 + 128 + h];
        }
        float u = 1.0f / (1.0f + expf(-(m2 + bb2)));
        float t = tanhf(m1 + bb1);
        out[(size_t)b * 128 + h] = u * t + (1.0f - u) * accs[i];
    }
}

extern "C" void kernel_launch(void* const* d_in, const int* in_sizes, int n_in,
                              void* d_out, int out_size, void* d_ws, size_t ws_size,
                              hipStream_t stream) {
    const float* in0 = (const float*)d_in[0];
    const float* in1 = (const float*)d_in[1];
    const float* st0 = (const float*)d_in[2];
    const float* st1 = (const float*)d_in[3];
    const float* W1  = (const float*)d_in[4];
    const float* b1  = (const float*)d_in[5];
    const float* W2  = (const float*)d_in[6];
    const float* b2  = (const float*)d_in[7];
    const float* W3  = (const float*)d_in[8];
    float* out = (float*)d_out;
    char* ws = (char*)d_ws;

    __hip_bfloat16* Wt   = (__hip_bfloat16*)(ws + WT_OFF);
    unsigned*       s_bf = (unsigned*)(ws + SBF_OFF);
    unsigned*       x_bf = (unsigned*)(ws + XBF_OFF);
    float*          Mp   = (float*)(ws + MP_OFF);

    prep_w<<<8192, 256, 0, stream>>>(W1, W2, (unsigned*)Wt);
    prep_sx<<<2048, 256, 0, stream>>>(in0, in1, st0, st1, s_bf, x_bf);
    gemm_p<<<512, 256, 0, stream>>>(Wt, (const unsigned short*)s_bf,
                                    (const __hip_bfloat16*)x_bf, Mp);
    epilogue<<<512, 256, 0, stream>>>(st0, st1, b1, b2, W3, Mp, out);
}

// Round 3
// 294.139 us; speedup vs baseline: 1.1971x; 1.1971x over previous
//
#include <hip/hip_runtime.h>
#include <hip/hip_bf16.h>
#include <stdint.h>

// ---------------------------------------------------------------------------
// TensorizedGRU: m[b,l] = sum_{j,k} s[b,j] x[b,k] W[l,j,k]  (l in [0,256): W1||W2)
// R3 restructure: m[b,l] = sum_j s[b,j] * (x_q . W[l,j,q]^T)  per k-quadrant q.
// A-operand (x) lives in registers, loop-invariant over the 32 j's of a quadrant;
// MFMA output macc is scaled by f32 s[b,j] into the running f32 accumulator.
// No P materialization, no A LDS traffic, s in full f32 precision.
// ws layout:
//   Wt   bf16 [256][65536]  @ 0         (33,554,432 B)  == W1||W2 cast to bf16
//   x_bf bf16 [4096][256]   @ 32MiB+2MiB ( 2,097,152 B)
//   Mpart f32 [8][4096][256]@ +2 MiB    (33,554,432 B)  split-K partials
// ---------------------------------------------------------------------------

typedef short bf8 __attribute__((ext_vector_type(8)));   // 8 bf16 = 4 VGPRs
typedef float f32x4 __attribute__((ext_vector_type(4)));

static constexpr size_t WT_OFF  = 0;
static constexpr size_t XBF_OFF = 33554432 + 2097152;    // keep old slot
static constexpr size_t MP_OFF  = XBF_OFF + 2097152;

// round-to-nearest-even f32 -> bf16 (finite inputs only)
__device__ __forceinline__ unsigned f2bf(float f) {
    unsigned u = __builtin_bit_cast(unsigned, f);
    return (u + 0x7fffu + ((u >> 16) & 1u)) >> 16;
}
__device__ __forceinline__ unsigned pack2bf(float a, float b) {
    return f2bf(a) | (f2bf(b) << 16);
}

// ---------------- prep: weights f32 -> bf16 (layout already [n][K]) ---------
__global__ void prep_w(const float* __restrict__ W1, const float* __restrict__ W2,
                       unsigned* __restrict__ Wt) {
    unsigned u = blockIdx.x * 256 + threadIdx.x;      // 2,097,152 units of 8 elems
    size_t e = (size_t)u * 8;
    unsigned n = (unsigned)(e >> 16);
    unsigned k = (unsigned)(e & 65535u);
    const float* src = (n < 128 ? W1 + ((size_t)n << 16)
                                : W2 + ((size_t)(n - 128) << 16)) + k;
    float4 a = ((const float4*)src)[0];
    float4 b = ((const float4*)src)[1];
    uint4 o;
    o.x = pack2bf(a.x, a.y); o.y = pack2bf(a.z, a.w);
    o.z = pack2bf(b.x, b.y); o.w = pack2bf(b.z, b.w);
    ((uint4*)Wt)[u] = o;
}

// ---------------- prep: x = in0||in1 -> bf16 --------------------------------
__global__ void prep_x(const float* __restrict__ in0, const float* __restrict__ in1,
                       unsigned* __restrict__ x_bf) {
    unsigned v = blockIdx.x * 256 + threadIdx.x;      // 262,144 units of 4 elems
    unsigned b = v >> 6;
    unsigned j4 = (v & 63u) * 4u;
    const float* src = (j4 < 128) ? (in0 + (size_t)b * 128 + j4)
                                  : (in1 + (size_t)b * 128 + (j4 - 128));
    float4 a = *(const float4*)src;
    uint2 o;
    o.x = pack2bf(a.x, a.y);
    o.y = pack2bf(a.z, a.w);
    ((uint2*)x_bf)[v] = o;
}

// ---------------- main GEMM: 128x128 tile, split-K=8 ------------------------
// grid 512 = 32 Mtiles x 2 Ntiles x 8 Ksplits; block 256 = 4 waves.
// Each wave: full 128 m-rows x 32 n-cols (nf in [0,2), mf in [0,8)).
__launch_bounds__(256, 2)
__global__ void gemm_p(const __hip_bfloat16* __restrict__ Wt,
                       const float* __restrict__ st0, const float* __restrict__ st1,
                       const __hip_bfloat16* __restrict__ x_bf,
                       float* __restrict__ Mpart) {
    const int bx = blockIdx.x;
    const int mt = bx & 31;
    const int nt = (bx >> 5) & 1;
    const int ks = bx >> 6;                 // 0..7, j-range [ks*32, ks*32+32)
    const int b0 = mt << 7, n0 = nt << 7;
    const int tid  = threadIdx.x;
    const int lane = tid & 63, wave = tid >> 6;   // wave = n-column group
    const int l15 = lane & 15, l4 = lane >> 4;

    // W tile: 128 n-rows x 64 k, XOR-swizzled 16B slots (global_load_lds forbids pad)
    __shared__ __align__(16) unsigned char Wl[16384];
    // s tile: [32 j][132 r] f32 (stride 132 pads banks; 16B-aligned rows: 132*4=528)
    __shared__ __align__(16) float Sl[32 * 132];

    // --- s init: Sl[j][r] = f32 s[b0+r][ks*32+j]
    for (int idx = tid; idx < 4096; idx += 256) {
        int r = idx >> 5, j = idx & 31;
        int jg = ks * 32 + j;
        float v = (jg < 128) ? st0[(size_t)(b0 + r) * 128 + jg]
                             : st1[(size_t)(b0 + r) * 128 + (jg - 128)];
        Sl[j * 132 + r] = v;
    }

    // --- staging precompute: 4 global_load_lds (16B/lane) per thread per chunk
    const __hip_bfloat16* wgp[4];
    unsigned char* wlp[4];
    #pragma unroll
    for (int i = 0; i < 4; ++i) {
        int slot = (wave * 4 + i) * 64 + lane;       // 16B-slot index 0..1023
        int r = slot >> 3;                           // n-row 0..127
        int g = (slot & 7) ^ (r & 7);                // swizzled k-group
        wgp[i] = Wt + (((size_t)(n0 + r)) << 16) + g * 8;
        wlp[i] = Wl + (wave * 4 + i) * 1024;         // wave-uniform base (+lane*16 by HW)
    }

    // --- B-frag read base: row = wave*32 + nf*16 + l15, swizzled group ^ (row&7)
    const unsigned char* pB = Wl + (wave * 32 + l15) * 128;
    const int be = lane & 7;
    const float* sB = Sl + l4 * 4;                   // + j*132 + mf*16

    f32x4 racc[8][2];
    #pragma unroll
    for (int mf = 0; mf < 8; ++mf)
        #pragma unroll
        for (int nf = 0; nf < 2; ++nf)
            racc[mf][nf] = (f32x4){0.f, 0.f, 0.f, 0.f};

    const f32x4 zacc = (f32x4){0.f, 0.f, 0.f, 0.f};

    __syncthreads();   // Sl visible (also covered by first in-loop barrier)

    for (int q = 0; q < 4; ++q) {
        // A-frags for this x-quadrant, loop-invariant over j:
        // a[mf][kst] = x[b0+mf*16+l15][q*64 + kst*32 + l4*8 .. +8]
        bf8 a[8][2];
        const __hip_bfloat16* xb = x_bf + q * 64 + l4 * 8;
        #pragma unroll
        for (int mf = 0; mf < 8; ++mf)
            #pragma unroll
            for (int kst = 0; kst < 2; ++kst)
                a[mf][kst] = *(const bf8*)(xb + (size_t)(b0 + mf * 16 + l15) * 256 + kst * 32);

        for (int j = 0; j < 32; ++j) {
            const int koff = (ks * 32 + j) * 256 + q * 64;
            #pragma unroll
            for (int i = 0; i < 4; ++i) {
                __builtin_amdgcn_global_load_lds(
                    (__attribute__((address_space(1))) const unsigned*)(const void*)(wgp[i] + koff),
                    (__attribute__((address_space(3))) unsigned*)(void*)wlp[i],
                    16, 0, 0);
            }
            __syncthreads();   // drain DMA; W chunk (j,q) + Sl visible

            // s values for rows mf*16 + l4*4 .. +4 at column j (broadcast reads)
            f32x4 sv[8];
            #pragma unroll
            for (int mf = 0; mf < 8; ++mf)
                sv[mf] = *(const f32x4*)(sB + j * 132 + mf * 16);

            #pragma unroll
            for (int nf = 0; nf < 2; ++nf) {
                const unsigned char* pBn = pB + nf * 2048;
                bf8 bf0 = *(const bf8*)(pBn + ((0 + l4) ^ be) * 16);  // kst=0
                bf8 bf1 = *(const bf8*)(pBn + ((4 + l4) ^ be) * 16);  // kst=1
                #pragma unroll
                for (int mf = 0; mf < 8; ++mf) {
                    f32x4 m0 = __builtin_amdgcn_mfma_f32_16x16x32_bf16(a[mf][0], bf0, zacc, 0, 0, 0);
                    m0 = __builtin_amdgcn_mfma_f32_16x16x32_bf16(a[mf][1], bf1, m0, 0, 0, 0);
                    racc[mf][nf] += sv[mf] * m0;    // f32 scale-accumulate
                }
            }
            __syncthreads();   // readers done before next chunk's DMA overwrites Wl
        }
    }

    // write split-K partials; C/D: row b = b0+mf*16+l4*4+r, col n = n0+wave*32+nf*16+l15
    float* mp = Mpart + ((size_t)ks << 20);
    #pragma unroll
    for (int mf = 0; mf < 8; ++mf)
        #pragma unroll
        for (int nf = 0; nf < 2; ++nf) {
            int b = b0 + mf * 16 + l4 * 4;
            int n = n0 + wave * 32 + nf * 16 + l15;
            #pragma unroll
            for (int r = 0; r < 4; ++r)
                mp[(size_t)(b + r) * 256 + n] = racc[mf][nf][r];
        }
}

// ---------------- epilogue: reduce split-K, s@W3, activations, blend --------
__global__ void epilogue(const float* __restrict__ st0, const float* __restrict__ st1,
                         const float* __restrict__ b1, const float* __restrict__ b2,
                         const float* __restrict__ W3, const float* __restrict__ Mpart,
                         float* __restrict__ out) {
    const int tid = threadIdx.x;
    const int h = tid & 127, rg = tid >> 7;          // rg in {0,1}
    const int bbase = blockIdx.x * 8;                // 8 rows per block
    __shared__ float srow[8][256];
    #pragma unroll
    for (int i = 0; i < 8; ++i) {
        int idx = i * 256 + tid;
        int r = idx >> 8, j = idx & 255;
        float v = (j < 128) ? st0[(size_t)(bbase + r) * 128 + j]
                            : st1[(size_t)(bbase + r) * 128 + (j - 128)];
        srow[r][j] = v;
    }
    __syncthreads();
    float acc0 = 0.f, acc1 = 0.f, acc2 = 0.f, acc3 = 0.f;
    for (int j = 0; j < 256; ++j) {
        float w = W3[j * 128 + h];
        acc0 += srow[rg][j] * w;
        acc1 += srow[rg + 2][j] * w;
        acc2 += srow[rg + 4][j] * w;
        acc3 += srow[rg + 6][j] * w;
    }
    float accs[4] = {acc0, acc1, acc2, acc3};
    float bb1 = b1[h], bb2 = b2[h];
    #pragma unroll
    for (int i = 0; i < 4; ++i) {
        int b = bbase + rg + i * 2;
        float m1 = 0.f, m2 = 0.f;
        #pragma unroll
        for (int k = 0; k < 8; ++k) {
            m1 += Mpart[((size_t)k << 20) + (size_t)b * 256 + h];
            m2 += Mpart[((size_t)k << 20) + (size_t)b * 256 + 128 + h];
        }
        float u = 1.0f / (1.0f + expf(-(m2 + bb2)));
        float t = tanhf(m1 + bb1);
        out[(size_t)b * 128 + h] = u * t + (1.0f - u) * accs[i];
    }
}

extern "C" void kernel_launch(void* const* d_in, const int* in_sizes, int n_in,
                              void* d_out, int out_size, void* d_ws, size_t ws_size,
                              hipStream_t stream) {
    const float* in0 = (const float*)d_in[0];
    const float* in1 = (const float*)d_in[1];
    const float* st0 = (const float*)d_in[2];
    const float* st1 = (const float*)d_in[3];
    const float* W1  = (const float*)d_in[4];
    const float* b1  = (const float*)d_in[5];
    const float* W2  = (const float*)d_in[6];
    const float* b2  = (const float*)d_in[7];
    const float* W3  = (const float*)d_in[8];
    float* out = (float*)d_out;
    char* ws = (char*)d_ws;

    __hip_bfloat16* Wt   = (__hip_bfloat16*)(ws + WT_OFF);
    unsigned*       x_bf = (unsigned*)(ws + XBF_OFF);
    float*          Mp   = (float*)(ws + MP_OFF);

    prep_w<<<8192, 256, 0, stream>>>(W1, W2, (unsigned*)Wt);
    prep_x<<<1024, 256, 0, stream>>>(in0, in1, x_bf);
    gemm_p<<<512, 256, 0, stream>>>(Wt, st0, st1, (const __hip_bfloat16*)x_bf, Mp);
    epilogue<<<512, 256, 0, stream>>>(st0, st1, b1, b2, W3, Mp, out);
}

// Round 4
// 276.016 us; speedup vs baseline: 1.2757x; 1.0657x over previous
//
#include <hip/hip_runtime.h>
#include <hip/hip_bf16.h>
#include <stdint.h>

// ---------------------------------------------------------------------------
// TensorizedGRU: m[b,l] = sum_{j,k} s[b,j] x[b,k] W[l,j,k]  (l in [0,256): W1||W2)
// R4: barrier-free K-loop. m[b,l] = sum_j s[b,j] * (x_q . W[l,j,q]^T).
//  - B-frags (W) loaded straight from global (16B contiguous per lane in [n][K]
//    layout) with depth-1 ping-pong prefetch -> no LDS for W, no __syncthreads
//    in the loop, loads stay in flight across chunks (vmcnt pipelining).
//  - A-frags (x) register-resident per k-quadrant; s f32 via LDS broadcast.
//  - ks = blockIdx & 7 pins each split-K slice to one XCD => 4MB W slice == L2.
//  - Mpart stores nontemporal (don't evict W from L2).
// ws layout:
//   Wt   bf16 [256][65536]  @ 0          (33,554,432 B)
//   x_bf bf16 [4096][256]   @ 32MiB+2MiB ( 2,097,152 B)
//   Mpart f32 [8][4096][256]@ +2MiB      (33,554,432 B)
// ---------------------------------------------------------------------------

typedef short bf8 __attribute__((ext_vector_type(8)));   // 8 bf16 = 4 VGPRs
typedef float f32x4 __attribute__((ext_vector_type(4)));

static constexpr size_t WT_OFF  = 0;
static constexpr size_t XBF_OFF = 33554432 + 2097152;
static constexpr size_t MP_OFF  = XBF_OFF + 2097152;

// round-to-nearest-even f32 -> bf16 (finite inputs only)
__device__ __forceinline__ unsigned f2bf(float f) {
    unsigned u = __builtin_bit_cast(unsigned, f);
    return (u + 0x7fffu + ((u >> 16) & 1u)) >> 16;
}
__device__ __forceinline__ unsigned pack2bf(float a, float b) {
    return f2bf(a) | (f2bf(b) << 16);
}

// ---------------- prep: W f32->bf16 (blocks 0..8191) + x (blocks 8192..9215)
__global__ void prep_wx(const float* __restrict__ W1, const float* __restrict__ W2,
                        const float* __restrict__ in0, const float* __restrict__ in1,
                        unsigned* __restrict__ Wt, unsigned* __restrict__ x_bf) {
    int bx = blockIdx.x;
    if (bx < 8192) {
        unsigned u = bx * 256 + threadIdx.x;          // 2,097,152 units of 8 elems
        size_t e = (size_t)u * 8;
        unsigned n = (unsigned)(e >> 16);
        unsigned k = (unsigned)(e & 65535u);
        const float* src = (n < 128 ? W1 + ((size_t)n << 16)
                                    : W2 + ((size_t)(n - 128) << 16)) + k;
        float4 a = ((const float4*)src)[0];
        float4 b = ((const float4*)src)[1];
        uint4 o;
        o.x = pack2bf(a.x, a.y); o.y = pack2bf(a.z, a.w);
        o.z = pack2bf(b.x, b.y); o.w = pack2bf(b.z, b.w);
        ((uint4*)Wt)[u] = o;
    } else {
        unsigned v = (bx - 8192) * 256 + threadIdx.x; // 262,144 units of 4 elems
        unsigned b = v >> 6;
        unsigned j4 = (v & 63u) * 4u;
        const float* src = (j4 < 128) ? (in0 + (size_t)b * 128 + j4)
                                      : (in1 + (size_t)b * 128 + (j4 - 128));
        float4 a = *(const float4*)src;
        uint2 o;
        o.x = pack2bf(a.x, a.y);
        o.y = pack2bf(a.z, a.w);
        ((uint2*)x_bf)[v] = o;
    }
}

// ---------------- main GEMM: 128x128 tile, split-K=8, barrier-free ----------
// grid 512: ks = bx&7 (XCD-pinned), nt = (bx>>3)&1, mt = bx>>4.
// block 256 = 4 waves; wave w owns n-cols [w*32, w*32+32), all 128 m-rows.
__launch_bounds__(256, 2)
__global__ void gemm_p(const __hip_bfloat16* __restrict__ Wt,
                       const float* __restrict__ st0, const float* __restrict__ st1,
                       const __hip_bfloat16* __restrict__ x_bf,
                       float* __restrict__ Mpart) {
    const int bx = blockIdx.x;
    const int ks = bx & 7;                  // split-K slice, pinned per XCD
    const int nt = (bx >> 3) & 1;
    const int mt = bx >> 4;
    const int b0 = mt << 7, n0 = nt << 7;
    const int tid  = threadIdx.x;
    const int lane = tid & 63, wave = tid >> 6;
    const int l15 = lane & 15, l4 = lane >> 4;

    // s tile: [32 j][132 r] f32 (pad to 132 -> broadcast-clean)
    __shared__ __align__(16) float Sl[32 * 132];
    for (int idx = tid; idx < 4096; idx += 256) {
        int r = idx >> 5, j = idx & 31;
        int jg = ks * 32 + j;
        float v = (jg < 128) ? st0[(size_t)(b0 + r) * 128 + jg]
                             : st1[(size_t)(b0 + r) * 128 + (jg - 128)];
        Sl[j * 132 + r] = v;
    }
    __syncthreads();                        // the ONLY barrier

    // B-frag base: lane l reads Wt[n0+wave*32+nf*16+l15][jk + kst*32 + l4*8 ..+8]
    const __hip_bfloat16* rb = Wt + ((size_t)(n0 + wave * 32 + l15) << 16) + l4 * 8;
    const float* sB = Sl + l4 * 4;

    f32x4 racc[8][2];
    #pragma unroll
    for (int mf = 0; mf < 8; ++mf)
        #pragma unroll
        for (int nf = 0; nf < 2; ++nf)
            racc[mf][nf] = (f32x4){0.f, 0.f, 0.f, 0.f};
    const f32x4 zacc = (f32x4){0.f, 0.f, 0.f, 0.f};

    // chunk c in [0,128): q = c>>5 (x-quadrant), j = c&31 (local j)
    // Wt column offset for chunk c: jk(c) = (ks*32 + (c&31))*256 + (c>>5)*64
    auto jkof = [&](int c) { return (ks * 32 + (c & 31)) * 256 + (c >> 5) * 64; };

    bf8 buf[2][2][2];                       // [ping][nf][kst]
    #pragma unroll
    for (int nf = 0; nf < 2; ++nf)
        #pragma unroll
        for (int kst = 0; kst < 2; ++kst)
            buf[0][nf][kst] = *(const bf8*)(rb + ((size_t)nf << 20) + jkof(0) + kst * 32);

    bf8 a[8][2];                            // x A-frags, reloaded at q boundary

    #pragma unroll 2
    for (int c = 0; c < 128; ++c) {
        const int pp = c & 1;
        const int q = c >> 5, j = c & 31;
        if (j == 0) {                       // new x-quadrant: reload A-frags
            const __hip_bfloat16* xb = x_bf + q * 64 + l4 * 8;
            #pragma unroll
            for (int mf = 0; mf < 8; ++mf)
                #pragma unroll
                for (int kst = 0; kst < 2; ++kst)
                    a[mf][kst] = *(const bf8*)(xb + (size_t)(b0 + mf * 16 + l15) * 256 + kst * 32);
        }
        // prefetch next chunk's B-frags (wraps to 0 on last iter: harmless)
        {
            const int c1 = (c + 1) & 127;
            const int jk1 = jkof(c1);
            #pragma unroll
            for (int nf = 0; nf < 2; ++nf)
                #pragma unroll
                for (int kst = 0; kst < 2; ++kst)
                    buf[pp ^ 1][nf][kst] = *(const bf8*)(rb + ((size_t)nf << 20) + jk1 + kst * 32);
        }
        // s broadcast values for this j
        f32x4 sv[8];
        #pragma unroll
        for (int mf = 0; mf < 8; ++mf)
            sv[mf] = *(const f32x4*)(sB + j * 132 + mf * 16);
        // 32 MFMA + f32 scale-accumulate
        #pragma unroll
        for (int nf = 0; nf < 2; ++nf) {
            bf8 bf0 = buf[pp][nf][0];
            bf8 bf1 = buf[pp][nf][1];
            #pragma unroll
            for (int mf = 0; mf < 8; ++mf) {
                f32x4 m0 = __builtin_amdgcn_mfma_f32_16x16x32_bf16(a[mf][0], bf0, zacc, 0, 0, 0);
                m0 = __builtin_amdgcn_mfma_f32_16x16x32_bf16(a[mf][1], bf1, m0, 0, 0, 0);
                racc[mf][nf] += sv[mf] * m0;
            }
        }
    }

    // nontemporal split-K partial stores (don't evict W slice from L2)
    float* mp = Mpart + ((size_t)ks << 20);
    #pragma unroll
    for (int mf = 0; mf < 8; ++mf)
        #pragma unroll
        for (int nf = 0; nf < 2; ++nf) {
            int b = b0 + mf * 16 + l4 * 4;
            int n = n0 + wave * 32 + nf * 16 + l15;
            #pragma unroll
            for (int r = 0; r < 4; ++r)
                __builtin_nontemporal_store(racc[mf][nf][r],
                                            &mp[(size_t)(b + r) * 256 + n]);
        }
}

// ---------------- epilogue: reduce split-K, s@W3, activations, blend --------
__global__ void epilogue(const float* __restrict__ st0, const float* __restrict__ st1,
                         const float* __restrict__ b1, const float* __restrict__ b2,
                         const float* __restrict__ W3, const float* __restrict__ Mpart,
                         float* __restrict__ out) {
    const int tid = threadIdx.x;
    const int h = tid & 127, rg = tid >> 7;          // rg in {0,1}
    const int bbase = blockIdx.x * 8;                // 8 rows per block
    __shared__ float srow[8][256];
    #pragma unroll
    for (int i = 0; i < 8; ++i) {
        int idx = i * 256 + tid;
        int r = idx >> 8, j = idx & 255;
        float v = (j < 128) ? st0[(size_t)(bbase + r) * 128 + j]
                            : st1[(size_t)(bbase + r) * 128 + (j - 128)];
        srow[r][j] = v;
    }
    __syncthreads();
    float acc0 = 0.f, acc1 = 0.f, acc2 = 0.f, acc3 = 0.f;
    for (int j = 0; j < 256; ++j) {
        float w = W3[j * 128 + h];
        acc0 += srow[rg][j] * w;
        acc1 += srow[rg + 2][j] * w;
        acc2 += srow[rg + 4][j] * w;
        acc3 += srow[rg + 6][j] * w;
    }
    float accs[4] = {acc0, acc1, acc2, acc3};
    float bb1 = b1[h], bb2 = b2[h];
    #pragma unroll
    for (int i = 0; i < 4; ++i) {
        int b = bbase + rg + i * 2;
        float m1 = 0.f, m2 = 0.f;
        #pragma unroll
        for (int k = 0; k < 8; ++k) {
            m1 += Mpart[((size_t)k << 20) + (size_t)b * 256 + h];
            m2 += Mpart[((size_t)k << 20) + (size_t)b * 256 + 128 + h];
        }
        float u = 1.0f / (1.0f + expf(-(m2 + bb2)));
        float t = tanhf(m1 + bb1);
        out[(size_t)b * 128 + h] = u * t + (1.0f - u) * accs[i];
    }
}

extern "C" void kernel_launch(void* const* d_in, const int* in_sizes, int n_in,
                              void* d_out, int out_size, void* d_ws, size_t ws_size,
                              hipStream_t stream) {
    const float* in0 = (const float*)d_in[0];
    const float* in1 = (const float*)d_in[1];
    const float* st0 = (const float*)d_in[2];
    const float* st1 = (const float*)d_in[3];
    const float* W1  = (const float*)d_in[4];
    const float* b1  = (const float*)d_in[5];
    const float* W2  = (const float*)d_in[6];
    const float* b2  = (const float*)d_in[7];
    const float* W3  = (const float*)d_in[8];
    float* out = (float*)d_out;
    char* ws = (char*)d_ws;

    __hip_bfloat16* Wt   = (__hip_bfloat16*)(ws + WT_OFF);
    unsigned*       x_bf = (unsigned*)(ws + XBF_OFF);
    float*          Mp   = (float*)(ws + MP_OFF);

    prep_wx<<<9216, 256, 0, stream>>>(W1, W2, in0, in1, (unsigned*)Wt, x_bf);
    gemm_p<<<512, 256, 0, stream>>>(Wt, st0, st1, (const __hip_bfloat16*)x_bf, Mp);
    epilogue<<<512, 256, 0, stream>>>(st0, st1, b1, b2, W3, Mp, out);
}